// Round 10
// baseline (190.084 us; speedup 1.0000x reference)
//
#include <hip/hip_runtime.h>
#include <hip/hip_bf16.h>

#define IDIM 256
#define GDIM 64
#define ODIM 512
#define KD   (IDIM * GDIM)
#define WS_NEED ((size_t)512 * 512 * 64 * 2)   // 32 MB bf16 image

typedef __attribute__((ext_vector_type(8))) short bhalf8;
typedef __attribute__((ext_vector_type(4))) float fvec4;
typedef __attribute__((ext_vector_type(4))) unsigned uvec4;

#define INV2PI 0.15915494309189535f
#define AS1 __attribute__((address_space(1)))
#define AS3 __attribute__((address_space(3)))

static __device__ __forceinline__ short bf16b(float v) {
    __hip_bfloat16 hb = __float2bfloat16(v);
    short s; __builtin_memcpy(&s, &hb, 2); return s;
}
static __device__ __forceinline__ unsigned cvtpk(float lo, float hi) {
    unsigned r;
    asm("v_cvt_pk_bf16_f32 %0, %1, %2" : "=v"(r) : "v"(lo), "v"(hi));
    return r;
}

// advance ONE chain (cos or sin) by two Chebyshev steps
#define ADVP(A,B,C2) do { float _t = __builtin_fmaf((C2),(B),-(A)); (A)=(B); (B)=_t; \
                          _t = __builtin_fmaf((C2),(B),-(A)); (A)=(B); (B)=_t; } while (0)

// counted boundary: wait own vmcnt(N), pin, barrier, pin
#define BOUND(N) do { asm volatile("s_waitcnt vmcnt(" #N ")" ::: "memory"); \
                      __builtin_amdgcn_sched_barrier(0); \
                      __builtin_amdgcn_s_barrier(); \
                      __builtin_amdgcn_sched_barrier(0); } while (0)
#define BOUND_LG() do { asm volatile("s_waitcnt lgkmcnt(0)" ::: "memory"); \
                      __builtin_amdgcn_sched_barrier(0); \
                      __builtin_amdgcn_s_barrier(); \
                      __builtin_amdgcn_sched_barrier(0); } while (0)

// ws image v2: tile b = i*2+h (512 tiles x 64KB). Row o (512): [cos 64B | sin 64B],
// each half 4x16B granules, granule g stored at position g ^ ((o>>1)&3).
// Multiplier of granule g slot u: 16g + 8h + u + 1.
__global__ void prep_b(const float* __restrict__ coeffs, short* __restrict__ ws) {
    const int b = blockIdx.x;          // 512: i*2+h
    const int i = b >> 1, h = b & 1;
    const int o = threadIdx.x;         // 512
    char* dst = (char*)(ws + ((size_t)b * 512 + o) * 64);
    const int key = (o >> 1) & 3;
#pragma unroll
    for (int z = 0; z < 2; ++z)
#pragma unroll
        for (int g = 0; g < 4; ++g) {
            const float* src = coeffs + ((size_t)z * ODIM + o) * KD
                             + (size_t)i * GDIM + 16 * g + 8 * h;
            fvec4 v0 = ((const fvec4*)src)[0];
            fvec4 v1 = ((const fvec4*)src)[1];
            bhalf8 pk;
#pragma unroll
            for (int u = 0; u < 4; ++u) { pk[u] = bf16b(v0[u]); pk[4 + u] = bf16b(v1[u]); }
            *(bhalf8*)(dst + z * 64 + (((g ^ key)) << 4)) = pk;
        }
}

__global__ void bias_init(const float* __restrict__ bias, float* __restrict__ out) {
    int idx = blockIdx.x * 256 + threadIdx.x;
    fvec4 bv = ((const fvec4*)bias)[idx & 127];
    ((fvec4*)out)[idx] = bv;
}

// 1024 blocks = 32 mt x 4 ot x 8 ks, 4 blocks/CU. Block 256 thr = 4 waves (1x4:
// wave owns 32 rows x 128 cols, acc[2][8]). Halves H=0..127: tile T=H>>1, z=H&1.
// 4 half-buffers (8KB), DMA 2 halves ahead, counted vmcnt(2) per boundary.
template<int USE_WS>
__global__ void __launch_bounds__(256, 4)
fkan_gemm(const float* __restrict__ x, const float* __restrict__ coeffs,
          const short* __restrict__ wsb, float* __restrict__ out) {
    __shared__ __align__(16) short B4[4][4096];   // 4 x 8KB (128 rows x 64B)
    __shared__ float  sl_rev[4][128];
    __shared__ float2 sl_cs[4][128];

    const int bx = blockIdx.x;
    const int xcd = bx & 7, j = bx >> 3;
    const int lg  = xcd * 4 + (j & 3);
    const int mt  = j >> 2;
    const int ot  = lg >> 3, ks = lg & 7;
    const int row0 = mt * 128, col0 = ot * 128;
    const int i0 = ks * 32;

    const int t = threadIdx.x;
    const int lane = t & 63, wid = t >> 6;
    const int q   = lane >> 4;                 // k-granule / A k-quarter
    const int key = ((lane & 15) >> 1) & 3;    // read-side swizzle key
    const int rA0 = wid * 32 + (lane & 15);
    const float m0f = (float)(16 * q + 1);

    fvec4 acc[2][8];
#pragma unroll
    for (int a = 0; a < 2; ++a)
#pragma unroll
        for (int b = 0; b < 8; ++b) acc[a][b] = (fvec4)0.0f;

    auto fill_sl = [&](int chunk) {
#pragma unroll
        for (int w = 0; w < 2; ++w) {
            int idx = t + w * 256;
            int il2 = idx & 3, r2 = idx >> 2;
            float xv = x[(size_t)(row0 + r2) * IDIM + i0 + chunk * 4 + il2];
            float rev = xv * INV2PI;
            float a = __builtin_amdgcn_fractf(rev);
            float2 cs;
            cs.x = __builtin_amdgcn_cosf(a);
            cs.y = __builtin_amdgcn_sinf(a);
            sl_rev[il2][r2] = rev;
            sl_cs[il2][r2] = cs;
        }
    };

    // DMA one half: 2 calls/wave (rows wid*32..+31), linear LDS, pre-swizzled src
    auto dma_half = [&](int Hh) {
        const int Tt = Hh >> 1, zz = Hh & 1, bs = Hh & 3;
        const char* srcl = (const char*)wsb + (((size_t)(i0 * 2 + Tt)) << 16)
                         + (size_t)(col0 + wid * 32 + (lane >> 2)) * 128
                         + zz * 64 + (lane & 3) * 16;
        __builtin_amdgcn_global_load_lds((const AS1 unsigned*)srcl,
            (AS3 unsigned*)&B4[bs][wid * 1024], 16, 0, 0);
        __builtin_amdgcn_global_load_lds((const AS1 unsigned*)(srcl + 16 * 128),
            (AS3 unsigned*)&B4[bs][wid * 1024 + 512], 16, 0, 0);
    };

    // fallback: stage BOTH halves of tile Tt (bufs (2T)&3, (2T+1)&3)
    auto stage_fb = [&](int Tt) {
        const int hh = Tt & 1, i = i0 + (Tt >> 1);
        const int o = t >> 1, zz = t & 1;
        const int keyo = (o >> 1) & 3;
        char* d0 = (char*)&B4[(2 * Tt + zz) & 3][o * 32];
#pragma unroll
        for (int g = 0; g < 4; ++g) {
            const float* src = coeffs + ((size_t)zz * ODIM + col0 + o) * KD
                             + (size_t)i * GDIM + 16 * g + 8 * hh;
            fvec4 v0 = ((const fvec4*)src)[0];
            fvec4 v1 = ((const fvec4*)src)[1];
            bhalf8 pk;
#pragma unroll
            for (int u = 0; u < 4; ++u) { pk[u] = bf16b(v0[u]); pk[4 + u] = bf16b(v1[u]); }
            *(bhalf8*)(d0 + ((g ^ keyo) << 4)) = pk;
        }
    };

    auto mfma_half = [&](int bs, bhalf8 af0, bhalf8 af1) {
        const char* Bb = (const char*)&B4[bs][0];
        const int goff = (q ^ key) << 4;
#pragma unroll
        for (int ch = 0; ch < 2; ++ch) {
            bhalf8 bq[4];
#pragma unroll
            for (int j2 = 0; j2 < 4; ++j2)
                bq[j2] = *(const bhalf8*)(Bb +
                    (size_t)((lane & 15) + (ch * 4 + j2) * 16) * 64 + goff);
            __builtin_amdgcn_s_setprio(1);
#pragma unroll
            for (int j2 = 0; j2 < 4; ++j2) {
                acc[0][ch * 4 + j2] = __builtin_amdgcn_mfma_f32_16x16x32_bf16(
                    af0, bq[j2], acc[0][ch * 4 + j2], 0, 0, 0);
                acc[1][ch * 4 + j2] = __builtin_amdgcn_mfma_f32_16x16x32_bf16(
                    af1, bq[j2], acc[1][ch * 4 + j2], 0, 0, 0);
            }
            __builtin_amdgcn_s_setprio(0);
        }
    };

    float ccA0, ccB0, ccA1, ccB1;   // cos chain state (per fm)
    float ssA0, ssB0, ssA1, ssB1;   // sin chain state
    float C20, C21;

    // ---- prologue ----
    fill_sl(0);
    if (USE_WS) {
        dma_half(0); dma_half(1);
        BOUND(2);
    } else {
        stage_fb(0);
        __syncthreads();
    }

#pragma unroll 1
    for (int H4 = 0; H4 < 32; ++H4) {
        const int Hb = H4 * 4;
        const int il = H4 & 3;
        bhalf8 af[2];

        // ========== PH0: z=0, seed both chains, fresh cos ==========
        if (USE_WS) {
            if (Hb > 0) {
                if ((Hb & 15) == 0) {          // fill boundary: double barrier
                    BOUND(2);
                    fill_sl(Hb >> 4);
                    BOUND_LG();
                } else {
                    BOUND(2);
                }
            }
            dma_half(Hb + 2);
        } else {
            if (Hb > 0) {
                __syncthreads();
                if ((Hb & 15) == 0) fill_sl(Hb >> 4);
                stage_fb(Hb >> 1);
                __syncthreads();
            }
        }
#pragma unroll
        for (int fm = 0; fm < 2; ++fm) {
            const int rr = rA0 + fm * 16;
            float rev = sl_rev[il][rr];
            float2 cs1 = sl_cs[il][rr];
            float C2x = cs1.x + cs1.x;
            float a0 = __builtin_amdgcn_fractf(rev * m0f);
            float c0 = __builtin_amdgcn_cosf(a0);
            float s0 = __builtin_amdgcn_sinf(a0);
            float cBv = __builtin_fmaf(c0, cs1.x, -(s0 * cs1.y));
            float sBv = __builtin_fmaf(s0, cs1.x,  c0 * cs1.y);
            uvec4 u; u[0] = cvtpk(c0, cBv);
            float A = c0, B = cBv;
            ADVP(A, B, C2x); u[1] = cvtpk(A, B);
            ADVP(A, B, C2x); u[2] = cvtpk(A, B);
            ADVP(A, B, C2x); u[3] = cvtpk(A, B);
            if (fm == 0) { ccA0 = A; ccB0 = B; ssA0 = s0; ssB0 = sBv; C20 = C2x; }
            else         { ccA1 = A; ccB1 = B; ssA1 = s0; ssB1 = sBv; C21 = C2x; }
            af[fm] = __builtin_bit_cast(bhalf8, u);
        }
        mfma_half(Hb & 3, af[0], af[1]);

        // ========== PH1: z=1, fresh sin (state saved for PH3) ==========
        if (USE_WS) { BOUND(2); dma_half(Hb + 3); }
#pragma unroll
        for (int fm = 0; fm < 2; ++fm) {
            float A = fm ? ssA1 : ssA0, B = fm ? ssB1 : ssB0;
            float C2x = fm ? C21 : C20;
            uvec4 u; u[0] = cvtpk(A, B);
            ADVP(A, B, C2x); u[1] = cvtpk(A, B);
            ADVP(A, B, C2x); u[2] = cvtpk(A, B);
            ADVP(A, B, C2x); u[3] = cvtpk(A, B);
            if (fm == 0) { ssA0 = A; ssB0 = B; } else { ssA1 = A; ssB1 = B; }
            af[fm] = __builtin_bit_cast(bhalf8, u);
        }
        mfma_half((Hb + 1) & 3, af[0], af[1]);

        // ========== PH2: z=0 of h=1, continue cos ==========
        if (USE_WS) {
            BOUND(2);
            if (Hb + 4 < 128) dma_half(Hb + 4);
        } else {
            __syncthreads();
            stage_fb((Hb >> 1) + 1);
            __syncthreads();
        }
#pragma unroll
        for (int fm = 0; fm < 2; ++fm) {
            float A = fm ? ccA1 : ccA0, B = fm ? ccB1 : ccB0;
            float C2x = fm ? C21 : C20;
            uvec4 u;
            ADVP(A, B, C2x); u[0] = cvtpk(A, B);
            ADVP(A, B, C2x); u[1] = cvtpk(A, B);
            ADVP(A, B, C2x); u[2] = cvtpk(A, B);
            ADVP(A, B, C2x); u[3] = cvtpk(A, B);
            af[fm] = __builtin_bit_cast(bhalf8, u);
        }
        mfma_half((Hb + 2) & 3, af[0], af[1]);

        // ========== PH3: z=1 of h=1, continue sin ==========
        if (USE_WS) {
            BOUND(2);
            if (Hb + 5 < 128) dma_half(Hb + 5);
        }
#pragma unroll
        for (int fm = 0; fm < 2; ++fm) {
            float A = fm ? ssA1 : ssA0, B = fm ? ssB1 : ssB0;
            float C2x = fm ? C21 : C20;
            uvec4 u;
            ADVP(A, B, C2x); u[0] = cvtpk(A, B);
            ADVP(A, B, C2x); u[1] = cvtpk(A, B);
            ADVP(A, B, C2x); u[2] = cvtpk(A, B);
            ADVP(A, B, C2x); u[3] = cvtpk(A, B);
            af[fm] = __builtin_bit_cast(bhalf8, u);
        }
        mfma_half((Hb + 3) & 3, af[0], af[1]);
    }

    // epilogue: C/D layout col=lane&15, row=(lane>>4)*4+r
#pragma unroll
    for (int fm = 0; fm < 2; ++fm) {
#pragma unroll
        for (int f = 0; f < 8; ++f) {
            int col = col0 + f * 16 + (lane & 15);
#pragma unroll
            for (int r = 0; r < 4; ++r) {
                int row = row0 + wid * 32 + fm * 16 + ((lane >> 4) * 4) + r;
                atomicAdd(&out[(size_t)row * ODIM + col], acc[fm][f][r]);
            }
        }
    }
}

extern "C" void kernel_launch(void* const* d_in, const int* in_sizes, int n_in,
                              void* d_out, int out_size, void* d_ws, size_t ws_size,
                              hipStream_t stream) {
    (void)in_sizes; (void)n_in; (void)out_size;
    const float* x      = (const float*)d_in[0];
    const float* coeffs = (const float*)d_in[1];
    const float* bias   = (const float*)d_in[2];
    float* out = (float*)d_out;

    const bool use_ws = (ws_size >= WS_NEED) && (((uintptr_t)d_ws & 15) == 0);

    bias_init<<<dim3(2048), dim3(256), 0, stream>>>(bias, out);
    if (use_ws) {
        prep_b<<<dim3(512), dim3(512), 0, stream>>>(coeffs, (short*)d_ws);
        fkan_gemm<1><<<dim3(1024), dim3(256), 0, stream>>>(x, coeffs, (const short*)d_ws, out);
    } else {
        fkan_gemm<0><<<dim3(1024), dim3(256), 0, stream>>>(x, coeffs, nullptr, out);
    }
}

// Round 11
// 176.092 us; speedup vs baseline: 1.0795x; 1.0795x over previous
//
#include <hip/hip_runtime.h>
#include <hip/hip_bf16.h>

#define IDIM 256
#define GDIM 64
#define ODIM 512
#define KD   (IDIM * GDIM)
#define TILE_SHORTS (512 * 64)
#define WS_NEED ((size_t)512 * TILE_SHORTS * 2)   // 32 MB bf16 image

typedef __attribute__((ext_vector_type(8))) short bhalf8;
typedef __attribute__((ext_vector_type(4))) float fvec4;
typedef __attribute__((ext_vector_type(4))) unsigned uvec4;

#define INV2PI 0.15915494309189535f
#define AS1 __attribute__((address_space(1)))
#define AS3 __attribute__((address_space(3)))

static __device__ __forceinline__ short bf16b(float v) {
    __hip_bfloat16 hb = __float2bfloat16(v);
    short s; __builtin_memcpy(&s, &hb, 2); return s;
}
static __device__ __forceinline__ unsigned cvtpk(float lo, float hi) {
    unsigned r;
    asm("v_cvt_pk_bf16_f32 %0, %1, %2" : "=v"(r) : "v"(lo), "v"(hi));
    return r;
}

// advance one chain (cos or sin) by two Chebyshev steps
#define ADVP(A,B,C2) do { float _t = __builtin_fmaf((C2),(B),-(A)); (A)=(B); (B)=_t; \
                          _t = __builtin_fmaf((C2),(B),-(A)); (A)=(B); (B)=_t; } while (0)

// ws image, K-permuted [proven R5/R8/R9]: tile b = i*2+h, row o (512),
// slot z*32 + Q*8 + u -> coeff[z][o][i][16Q + 8h + u]; rows 128 B,
// XOR-swizzled 16B granules (^(o&7)<<4).
__global__ void prep_b(const float* __restrict__ coeffs, short* __restrict__ ws) {
    const int b = blockIdx.x;          // 512: i*2+h
    const int i = b >> 1, h = b & 1;
    const int o = threadIdx.x;         // 512
    short* dst = ws + ((size_t)b * 512 + o) * 64;
    const int swz = (o & 7) << 4;
#pragma unroll
    for (int j = 0; j < 8; ++j) {      // granule: z = j>>2, Q = j&3
        const int z = j >> 2, Qq = j & 3;
        const float* src = coeffs + ((size_t)z * ODIM + o) * KD
                         + (size_t)i * GDIM + 16 * Qq + 8 * h;
        fvec4 v0 = ((const fvec4*)src)[0];
        fvec4 v1 = ((const fvec4*)src)[1];
        bhalf8 pk;
#pragma unroll
        for (int u = 0; u < 4; ++u) { pk[u] = bf16b(v0[u]); pk[4 + u] = bf16b(v1[u]); }
        *(bhalf8*)((char*)dst + ((j * 16) ^ swz)) = pk;
    }
}

__global__ void bias_init(const float* __restrict__ bias, float* __restrict__ out) {
    int idx = blockIdx.x * 256 + threadIdx.x;
    fvec4 bv = ((const fvec4*)bias)[idx & 127];
    ((fvec4*)out)[idx] = bv;
}

// Fence proven R8/R9: asm drain of LDS-DMA (vmcnt) + sched pin + __syncthreads.
#define FENCE() do { asm volatile("s_waitcnt vmcnt(0) lgkmcnt(0)" ::: "memory"); \
                     __builtin_amdgcn_sched_barrier(0); \
                     __syncthreads(); } while (0)

// 1024 blocks = 32 mt x 4 ot x 8 ks, 4 blocks/CU. Block 256 thr = 4 waves (1x4:
// wave owns 32 rows x 128 cols, acc[2][8]). Per tile T (i=T>>1, h=T&1): ONE
// barrier. A-fragments produced one phase ahead (afs(T) under cos-MFMA,
// afc(T+1) under sin-MFMA) so the post-barrier path is ds_read->MFMA only.
// Seed panel is wave-local (1x4 => rows private per wave): fills are per-wave
// LDS writes at T==6 mod 8, ordered by the tile-end FENCE; no fill barriers.
template<int USE_WS>
__global__ void __launch_bounds__(256, 4)
fkan_gemm(const float* __restrict__ x, const float* __restrict__ coeffs,
          const short* __restrict__ wsb, float* __restrict__ out) {
    __shared__ __align__(16) short B_lds[2][128 * 64];   // 32 KB
    __shared__ float  sl_rev[4][128];                    // 2 KB (wave-partitioned rows)
    __shared__ float2 sl_cs[4][128];                     // 4 KB

    const int bx = blockIdx.x;
    const int xcd = bx & 7, j = bx >> 3;
    const int lg  = xcd * 4 + (j & 3);
    const int mt  = j >> 2;
    const int ot  = lg >> 3, ks = lg & 7;
    const int row0 = mt * 128, col0 = ot * 128;
    const int i0 = ks * 32;

    const int t = threadIdx.x;
    const int lane = t & 63, wid = t >> 6;
    const int kl  = (lane >> 4) * 16;
    const int msk = (lane & 7) << 4;
    const int rA0 = wid * 32 + (lane & 15);
    const float m0f = (float)(16 * (lane >> 4) + 1);

    fvec4 acc[2][8];
#pragma unroll
    for (int a = 0; a < 2; ++a)
#pragma unroll
        for (int b = 0; b < 8; ++b) acc[a][b] = (fvec4)0.0f;

    // wave-local seed panel fill: each wave covers its own 32 rows x 4 i's.
    auto fill_sl = [&](int chunk) {
#pragma unroll
        for (int w2 = 0; w2 < 2; ++w2) {
            int idx = lane + w2 * 64;               // 0..127
            int il2 = idx & 3, r2 = wid * 32 + (idx >> 2);
            float xv = x[(size_t)(row0 + r2) * IDIM + i0 + chunk * 4 + il2];
            float rev = xv * INV2PI;
            float a = __builtin_amdgcn_fractf(rev);
            float2 cs;
            cs.x = __builtin_amdgcn_cosf(a);
            cs.y = __builtin_amdgcn_sinf(a);
            sl_rev[il2][r2] = rev;
            sl_cs[il2][r2] = cs;
        }
    };

    auto dmaB = [&](int T1) {
        const short* src = wsb + (size_t)(i0 * 2 + T1) * TILE_SHORTS
                         + (size_t)col0 * 64 + (size_t)t * 8;
        const int bsel = T1 & 1;
#pragma unroll
        for (int q = 0; q < 4; ++q)
            __builtin_amdgcn_global_load_lds(
                (const AS1 unsigned*)(src + q * 2048),
                (AS3 unsigned*)&B_lds[bsel][q * 2048 + wid * 512],
                16, 0, 0);
    };

    auto stage_fb = [&](int T1) {   // fallback staging (no ws)
        const int bsel = T1 & 1;
        const int i = i0 + (T1 >> 1), hh = T1 & 1;
        const int o = t >> 1, z = t & 1;
        char* drow = (char*)&B_lds[bsel][o * 64];
        const int swz = (o & 7) << 4;
#pragma unroll
        for (int Qq = 0; Qq < 4; ++Qq) {
            const float* src = coeffs + ((size_t)z * ODIM + col0 + o) * KD
                             + (size_t)i * GDIM + 16 * Qq + 8 * hh;
            fvec4 v0 = ((const fvec4*)src)[0];
            fvec4 v1 = ((const fvec4*)src)[1];
            bhalf8 pk;
#pragma unroll
            for (int u = 0; u < 4; ++u) { pk[u] = bf16b(v0[u]); pk[4 + u] = bf16b(v1[u]); }
            *(bhalf8*)(drow + ((z * 64 + Qq * 16) ^ swz)) = pk;
        }
    };

    // chain state (static names; rule #20)
    float ccA0, ccB0, ccA1, ccB1;   // cos chain per fm
    float ssA0, ssB0, ssA1, ssB1;   // sin chain per fm
    float C20, C21;
    bhalf8 afc[2], afs[2];

    // seed for even tile Te: panel -> afc(Te) + fresh chain states
    auto seed_even = [&](int Te) {
        const int il = (Te >> 1) & 3;
#pragma unroll
        for (int fm = 0; fm < 2; ++fm) {
            const int rr = rA0 + fm * 16;
            float rev = sl_rev[il][rr];
            float2 cs1 = sl_cs[il][rr];
            float C2x = cs1.x + cs1.x;
            float a0 = __builtin_amdgcn_fractf(rev * m0f);
            float c0 = __builtin_amdgcn_cosf(a0);
            float s0 = __builtin_amdgcn_sinf(a0);
            float cBv = __builtin_fmaf(c0, cs1.x, -(s0 * cs1.y));   // cos((m0+1)x)
            float sBv = __builtin_fmaf(s0, cs1.x,  c0 * cs1.y);     // sin((m0+1)x)
            uvec4 u; u[0] = cvtpk(c0, cBv);
            float A = c0, B = cBv;
            ADVP(A, B, C2x); u[1] = cvtpk(A, B);
            ADVP(A, B, C2x); u[2] = cvtpk(A, B);
            ADVP(A, B, C2x); u[3] = cvtpk(A, B);
            if (fm == 0) { ccA0 = A; ccB0 = B; ssA0 = s0; ssB0 = sBv; C20 = C2x; }
            else         { ccA1 = A; ccB1 = B; ssA1 = s0; ssB1 = sBv; C21 = C2x; }
            afc[fm] = __builtin_bit_cast(bhalf8, u);
        }
    };

    auto mfma_z = [&](const char* Bb, int z, bhalf8 a0f, bhalf8 a1f) {
        const int koff = (z * 64 + kl) ^ msk;
#pragma unroll
        for (int half = 0; half < 2; ++half) {
            bhalf8 bq[4];
#pragma unroll
            for (int f4 = 0; f4 < 4; ++f4)
                bq[f4] = *(const bhalf8*)(Bb +
                    (size_t)(half * 64 + f4 * 16 + (lane & 15)) * 128 + koff);
            __builtin_amdgcn_s_setprio(1);
#pragma unroll
            for (int f4 = 0; f4 < 4; ++f4) {
                acc[0][half * 4 + f4] = __builtin_amdgcn_mfma_f32_16x16x32_bf16(
                    a0f, bq[f4], acc[0][half * 4 + f4], 0, 0, 0);
                acc[1][half * 4 + f4] = __builtin_amdgcn_mfma_f32_16x16x32_bf16(
                    a1f, bq[f4], acc[1][half * 4 + f4], 0, 0, 0);
            }
            __builtin_amdgcn_s_setprio(0);
        }
    };

    // ---- prologue ----
    fill_sl(0);
    asm volatile("s_waitcnt lgkmcnt(0)" ::: "memory");
    __builtin_amdgcn_sched_barrier(0);
    seed_even(0);                      // afc(0) + chain states
    if (USE_WS) { dmaB(0); FENCE(); }
    else        { __syncthreads(); }

#pragma unroll 1
    for (int T = 0; T < 64; ++T) {
        if (USE_WS) {
            if ((T & 7) == 6 && T < 62) fill_sl((T + 2) >> 3);   // wave-local, no barrier
            if (T < 63) dmaB(T + 1);
            __builtin_amdgcn_sched_barrier(0);
        } else {
            if ((T & 7) == 6 && T < 62) fill_sl((T + 2) >> 3);
            stage_fb(T);
            __syncthreads();
        }

        const char* Bb = (const char*)&B_lds[T & 1][0];

        // ---- cos phase: MFMA with afc (ready); produce afs(T) in its shadow ----
        mfma_z(Bb, 0, afc[0], afc[1]);
        if ((T & 1) == 0) {
#pragma unroll
            for (int fm = 0; fm < 2; ++fm) {          // fresh sin from seeded state
                float A = fm ? ssA1 : ssA0, B = fm ? ssB1 : ssB0;
                float C2x = fm ? C21 : C20;
                uvec4 u; u[0] = cvtpk(A, B);
                ADVP(A, B, C2x); u[1] = cvtpk(A, B);
                ADVP(A, B, C2x); u[2] = cvtpk(A, B);
                ADVP(A, B, C2x); u[3] = cvtpk(A, B);
                if (fm == 0) { ssA0 = A; ssB0 = B; } else { ssA1 = A; ssB1 = B; }
                afs[fm] = __builtin_bit_cast(bhalf8, u);
            }
        } else {
#pragma unroll
            for (int fm = 0; fm < 2; ++fm) {          // continue sin chain
                float A = fm ? ssA1 : ssA0, B = fm ? ssB1 : ssB0;
                float C2x = fm ? C21 : C20;
                uvec4 u;
                ADVP(A, B, C2x); u[0] = cvtpk(A, B);
                ADVP(A, B, C2x); u[1] = cvtpk(A, B);
                ADVP(A, B, C2x); u[2] = cvtpk(A, B);
                ADVP(A, B, C2x); u[3] = cvtpk(A, B);
                afs[fm] = __builtin_bit_cast(bhalf8, u);
            }
        }

        // ---- sin phase: MFMA with afs; produce afc(T+1) in its shadow ----
        mfma_z(Bb, 1, afs[0], afs[1]);
        if (T < 63) {
            if ((T & 1) == 0) {
#pragma unroll
                for (int fm = 0; fm < 2; ++fm) {      // T+1 odd: continue cos chain
                    float A = fm ? ccA1 : ccA0, B = fm ? ccB1 : ccB0;
                    float C2x = fm ? C21 : C20;
                    uvec4 u;
                    ADVP(A, B, C2x); u[0] = cvtpk(A, B);
                    ADVP(A, B, C2x); u[1] = cvtpk(A, B);
                    ADVP(A, B, C2x); u[2] = cvtpk(A, B);
                    ADVP(A, B, C2x); u[3] = cvtpk(A, B);
                    afc[fm] = __builtin_bit_cast(bhalf8, u);
                }
            } else {
                seed_even(T + 1);                     // T+1 even: seed next i
            }
        }

        if (USE_WS) FENCE(); else __syncthreads();
    }

    // epilogue: C/D layout col=lane&15, row=(lane>>4)*4+r
#pragma unroll
    for (int fm = 0; fm < 2; ++fm) {
#pragma unroll
        for (int f = 0; f < 8; ++f) {
            int col = col0 + f * 16 + (lane & 15);
#pragma unroll
            for (int r = 0; r < 4; ++r) {
                int row = row0 + wid * 32 + fm * 16 + ((lane >> 4) * 4) + r;
                atomicAdd(&out[(size_t)row * ODIM + col], acc[fm][f][r]);
            }
        }
    }
}

extern "C" void kernel_launch(void* const* d_in, const int* in_sizes, int n_in,
                              void* d_out, int out_size, void* d_ws, size_t ws_size,
                              hipStream_t stream) {
    (void)in_sizes; (void)n_in; (void)out_size;
    const float* x      = (const float*)d_in[0];
    const float* coeffs = (const float*)d_in[1];
    const float* bias   = (const float*)d_in[2];
    float* out = (float*)d_out;

    const bool use_ws = (ws_size >= WS_NEED) && (((uintptr_t)d_ws & 15) == 0);

    bias_init<<<dim3(2048), dim3(256), 0, stream>>>(bias, out);
    if (use_ws) {
        prep_b<<<dim3(512), dim3(512), 0, stream>>>(coeffs, (short*)d_ws);
        fkan_gemm<1><<<dim3(1024), dim3(256), 0, stream>>>(x, coeffs, (const short*)d_ws, out);
    } else {
        fkan_gemm<0><<<dim3(1024), dim3(256), 0, stream>>>(x, coeffs, nullptr, out);
    }
}